// Round 1
// baseline (44.740 us; speedup 1.0000x reference)
//
#include <hip/hip_runtime.h>

#define BB 2
#define CC 8
#define DD 4
#define HH 256
#define WW 384

__global__ __launch_bounds__(256) void cqi3d_kernel(const float* __restrict__ x,
                                                    float* __restrict__ coords,
                                                    float* __restrict__ ymax) {
    const int idx = blockIdx.x * blockDim.x + threadIdx.x;
    const int total = BB * CC * DD * HH * WW;
    if (idx >= total) return;

    const int w = idx % WW;
    int t = idx / WW;
    const int h = t % HH;
    t /= HH;
    const int d = t % DD;
    const int bc = t / DD;  // b*C + c

    // edge-clamped neighbor indices
    const int zd[3] = {d > 0 ? d - 1 : 0, d, d < DD - 1 ? d + 1 : DD - 1};
    const int zh[3] = {h > 0 ? h - 1 : 0, h, h < HH - 1 ? h + 1 : HH - 1};
    const int zw[3] = {w > 0 ? w - 1 : 0, w, w < WW - 1 ? w + 1 : WW - 1};

    float v[3][3][3];
#pragma unroll
    for (int i = 0; i < 3; ++i) {
#pragma unroll
        for (int j = 0; j < 3; ++j) {
            const float* row = x + (((size_t)bc * DD + zd[i]) * HH + zh[j]) * WW;
#pragma unroll
            for (int k = 0; k < 3; ++k) v[i][j][k] = row[zw[k]];
        }
    }

    const float c = v[1][1][1];

    // first-order gradients (depth flipped: b2 = f(-1)-f(+1))
    const float b0 = 0.5f * (v[1][1][2] - v[1][1][0]);
    const float b1 = 0.5f * (v[1][2][1] - v[1][0][1]);
    const float b2 = 0.5f * (v[0][1][1] - v[2][1][1]);

    // second-order (Hessian)
    const float dxx = v[1][1][2] - 2.0f * c + v[1][1][0];
    const float dyy = v[1][2][1] - 2.0f * c + v[1][0][1];
    const float dss = v[2][1][1] - 2.0f * c + v[0][1][1];
    const float dxy = 0.25f * (v[1][0][0] - v[1][0][2] - v[1][2][0] + v[1][2][2]);
    const float dys = 0.25f * (-v[0][0][1] + v[0][2][1] + v[2][0][1] - v[2][2][1]);
    const float dxs = 0.25f * (-v[0][1][0] + v[0][1][2] + v[2][1][0] - v[2][1][2]);

    // 3x3x3 NMS: center equals window max (clamped reads can't change the max)
    float mx = v[0][0][0];
#pragma unroll
    for (int i = 0; i < 3; ++i)
#pragma unroll
        for (int j = 0; j < 3; ++j)
#pragma unroll
            for (int k = 0; k < 3; ++k) mx = fmaxf(mx, v[i][j][k]);
    const bool nms = (c == mx);

    // adjugate / det symmetric solve
    const float c00 = dyy * dss - dys * dys;
    const float c01 = dxs * dys - dxy * dss;
    const float c02 = dxy * dys - dxs * dyy;
    const float c11 = dxx * dss - dxs * dxs;
    const float c12 = dxy * dxs - dxx * dys;
    const float c22 = dxx * dyy - dxy * dxy;
    const float det = dxx * c00 + dxy * c01 + dxs * c02;

    const bool ok = nms && (det != 0.0f);
    const float invdet = 1.0f / (det == 0.0f ? 1.0f : det);
    const float u0 = (c00 * b0 + c01 * b1 + c02 * b2) * invdet;
    const float u1 = (c01 * b0 + c11 * b1 + c12 * b2) * invdet;
    const float u2 = (c02 * b0 + c12 * b1 + c22 * b2) * invdet;

    float d0 = ok ? -u0 : 0.0f;
    float d1 = ok ? -u1 : 0.0f;
    float d2 = ok ? -u2 : 0.0f;

    const bool small = fmaxf(fmaxf(fabsf(d0), fabsf(d1)), fabsf(d2)) <= 0.7f;
    if (!small) { d0 = 0.0f; d1 = 0.0f; d2 = 0.0f; }

    const float dE = 0.5f * (b0 * d0 + b1 * d1 + b2 * d2);
    const float y = c + dE + (ok ? 10.0f : 0.0f);

    // outputs: coords (B,C,3,D,H,W) then y (B,C,D,H,W)
    const size_t plane = (size_t)HH * WW;
    const size_t cbase = (((size_t)bc * 3) * DD + d) * plane + (size_t)h * WW + w;
    coords[cbase]                      = (float)d + d2;
    coords[cbase + (size_t)DD * plane] = (float)w + d0;
    coords[cbase + (size_t)2 * DD * plane] = (float)h + d1;
    ymax[idx] = y;
}

extern "C" void kernel_launch(void* const* d_in, const int* in_sizes, int n_in,
                              void* d_out, int out_size, void* d_ws, size_t ws_size,
                              hipStream_t stream) {
    const float* x = (const float*)d_in[0];
    float* out = (float*)d_out;
    float* coords = out;                                        // B*C*3*D*H*W
    float* ymax = out + (size_t)BB * CC * 3 * DD * HH * WW;     // B*C*D*H*W

    const int total = BB * CC * DD * HH * WW;
    const int block = 256;
    const int grid = (total + block - 1) / block;
    cqi3d_kernel<<<grid, block, 0, stream>>>(x, coords, ymax);
}

// Round 2
// 28.340 us; speedup vs baseline: 1.5787x; 1.5787x over previous
//
#include <hip/hip_runtime.h>

#define BB 2
#define CC 8
#define DD 4
#define HH 256
#define WW 384
#define WV 4
#define WT (WW / WV)

__global__ __launch_bounds__(256) void cqi3d_kernel(const float* __restrict__ x,
                                                    float* __restrict__ coords,
                                                    float* __restrict__ ymax) {
    const int tid = blockIdx.x * blockDim.x + threadIdx.x;
    const int nthreads = BB * CC * HH * WT;
    if (tid >= nthreads) return;

    const int wt = tid % WT;
    int t = tid / WT;
    const int h = t % HH;
    const int bc = t / HH;

    const int w0 = wt * WV;

    const int hm = h > 0 ? h - 1 : 0;
    const int hp = h < HH - 1 ? h + 1 : HH - 1;
    const int hr[3] = {hm, h, hp};
    const int wl = w0 > 0 ? w0 - 1 : 0;            // clamped left neighbor
    const int wr = (w0 + WV < WW) ? w0 + WV : WW - 1;  // clamped right neighbor

    // register tile: rb[plane][hrow][x], x = 0..5 covering w0-1 .. w0+4 (clamped)
    float rb[DD][3][WV + 2];
#pragma unroll
    for (int p = 0; p < DD; ++p) {
#pragma unroll
        for (int j = 0; j < 3; ++j) {
            const float* row = x + (((size_t)bc * DD + p) * HH + hr[j]) * WW;
            const float4 v4 = *reinterpret_cast<const float4*>(row + w0);
            rb[p][j][1] = v4.x;
            rb[p][j][2] = v4.y;
            rb[p][j][3] = v4.z;
            rb[p][j][4] = v4.w;
            rb[p][j][0] = row[wl];
            rb[p][j][5] = row[wr];
        }
    }

    // vertical (h) max per plane per x — shared NMS partials
    float vm[DD][WV + 2];
#pragma unroll
    for (int p = 0; p < DD; ++p)
#pragma unroll
        for (int xx = 0; xx < WV + 2; ++xx)
            vm[p][xx] = fmaxf(fmaxf(rb[p][0][xx], rb[p][1][xx]), rb[p][2][xx]);

    const size_t plane = (size_t)HH * WW;

#pragma unroll
    for (int d = 0; d < DD; ++d) {
        const int i0 = d > 0 ? d - 1 : 0;           // d-1 clamped
        const int i1 = d;
        const int i2 = d < DD - 1 ? d + 1 : DD - 1; // d+1 clamped

        // depth max of vertical maxes for this output d
        float dm[WV + 2];
#pragma unroll
        for (int xx = 0; xx < WV + 2; ++xx)
            dm[xx] = fmaxf(fmaxf(vm[i0][xx], vm[i1][xx]), vm[i2][xx]);

        float yv[WV], o0[WV], o1[WV], o2[WV];
#pragma unroll
        for (int kk = 0; kk < WV; ++kk) {
            const int q = kk + 1;  // center x-index in the 6-wide window
            const float c = rb[i1][1][q];

            // first-order gradients (depth flipped: b2 = f(d-1) - f(d+1))
            const float b0 = 0.5f * (rb[i1][1][q + 1] - rb[i1][1][q - 1]);
            const float b1 = 0.5f * (rb[i1][2][q] - rb[i1][0][q]);
            const float b2 = 0.5f * (rb[i0][1][q] - rb[i2][1][q]);

            // Hessian
            const float dxx = rb[i1][1][q + 1] - 2.0f * c + rb[i1][1][q - 1];
            const float dyy = rb[i1][2][q] - 2.0f * c + rb[i1][0][q];
            const float dss = rb[i2][1][q] - 2.0f * c + rb[i0][1][q];
            const float dxy = 0.25f * (rb[i1][0][q - 1] - rb[i1][0][q + 1] -
                                       rb[i1][2][q - 1] + rb[i1][2][q + 1]);
            const float dys = 0.25f * (-rb[i0][0][q] + rb[i0][2][q] +
                                       rb[i2][0][q] - rb[i2][2][q]);
            const float dxs = 0.25f * (-rb[i0][1][q - 1] + rb[i0][1][q + 1] +
                                       rb[i2][1][q - 1] - rb[i2][1][q + 1]);

            // NMS: center equals 3x3x3 window max
            const float mx = fmaxf(fmaxf(dm[q - 1], dm[q]), dm[q + 1]);
            const bool nms = (c == mx);

            // adjugate / det symmetric solve
            const float c00 = dyy * dss - dys * dys;
            const float c01 = dxs * dys - dxy * dss;
            const float c02 = dxy * dys - dxs * dyy;
            const float c11 = dxx * dss - dxs * dxs;
            const float c12 = dxy * dxs - dxx * dys;
            const float c22 = dxx * dyy - dxy * dxy;
            const float det = dxx * c00 + dxy * c01 + dxs * c02;

            const bool ok = nms && (det != 0.0f);
            const float invdet = 1.0f / (det == 0.0f ? 1.0f : det);
            const float u0 = (c00 * b0 + c01 * b1 + c02 * b2) * invdet;
            const float u1 = (c01 * b0 + c11 * b1 + c12 * b2) * invdet;
            const float u2 = (c02 * b0 + c12 * b1 + c22 * b2) * invdet;

            float d0 = ok ? -u0 : 0.0f;
            float d1 = ok ? -u1 : 0.0f;
            float d2 = ok ? -u2 : 0.0f;

            const bool small = fmaxf(fmaxf(fabsf(d0), fabsf(d1)), fabsf(d2)) <= 0.7f;
            if (!small) { d0 = 0.0f; d1 = 0.0f; d2 = 0.0f; }

            const float dE = 0.5f * (b0 * d0 + b1 * d1 + b2 * d2);
            yv[kk] = c + dE + (ok ? 10.0f : 0.0f);
            o2[kk] = (float)d + d2;
            o0[kk] = (float)(w0 + kk) + d0;
            o1[kk] = (float)h + d1;
        }

        // vectorized stores
        const size_t ybase = (((size_t)bc * DD + d) * HH + h) * WW + w0;
        *reinterpret_cast<float4*>(ymax + ybase) = make_float4(yv[0], yv[1], yv[2], yv[3]);

        const size_t cbase = (((size_t)bc * 3) * DD + d) * plane + (size_t)h * WW + w0;
        *reinterpret_cast<float4*>(coords + cbase) =
            make_float4(o2[0], o2[1], o2[2], o2[3]);                 // ch 0: d + d2
        *reinterpret_cast<float4*>(coords + cbase + DD * plane) =
            make_float4(o0[0], o0[1], o0[2], o0[3]);                 // ch 1: w + d0
        *reinterpret_cast<float4*>(coords + cbase + 2 * DD * plane) =
            make_float4(o1[0], o1[1], o1[2], o1[3]);                 // ch 2: h + d1
    }
}

extern "C" void kernel_launch(void* const* d_in, const int* in_sizes, int n_in,
                              void* d_out, int out_size, void* d_ws, size_t ws_size,
                              hipStream_t stream) {
    const float* x = (const float*)d_in[0];
    float* out = (float*)d_out;
    float* coords = out;                                    // B*C*3*D*H*W
    float* ymax = out + (size_t)BB * CC * 3 * DD * HH * WW; // B*C*D*H*W

    const int nthreads = BB * CC * HH * WT;
    const int block = 256;
    const int grid = (nthreads + block - 1) / block;
    cqi3d_kernel<<<grid, block, 0, stream>>>(x, coords, ymax);
}